// Round 6
// baseline (257.140 us; speedup 1.0000x reference)
//
#include <hip/hip_runtime.h>
#include <hip/hip_bf16.h>
#include <stdint.h>

typedef __attribute__((ext_vector_type(8))) short short8;
typedef __attribute__((ext_vector_type(4))) float floatx4;

#define HD 64
#define D_IN 1024
#define TLEN 4096
#define NB 4
#define PPB 144    // M=128 t-tiles: sum_{t=0}^{31} ceil((2t+2)/8)
#define LDP 72     // padded stride for P buffer (bf16 elems), 144 B (16B-aligned)
#define SL2E 0.18033688011112042f   // (1/sqrt(64)) * log2(e), folded into k

__device__ __forceinline__ short f2bf(float f) {
    union { float f; uint32_t u; } v{f};
    uint32_t u = v.u;
    uint32_t r = (u + 0x7FFFu + ((u >> 16) & 1u)) >> 16;
    return (short)r;
}

__device__ __forceinline__ uint32_t pk2(float a, float b) {
    __hip_bfloat162 h = __float22bfloat162_rn(float2{a, b});
    union { __hip_bfloat162 h; uint32_t u; } c{h};
    return c.u;
}

// async 16-B global->LDS copy (fire-and-forget, no VGPR round trip)
__device__ __forceinline__ void ld_lds16(const void* g, void* l) {
    __builtin_amdgcn_global_load_lds(
        (const __attribute__((address_space(1))) uint32_t*)g,
        (__attribute__((address_space(3))) uint32_t*)l, 16, 0, 0);
}

// ---------------- kernel 0: W -> fragment-major bf16 wt + zero split counters ----
__global__ __launch_bounds__(256) void prep_w(const float* __restrict__ Wk,
                                              const float* __restrict__ Wq,
                                              const float* __restrict__ Wv,
                                              short* __restrict__ wt,
                                              int* __restrict__ pCnt) {
    if (blockIdx.x == 0 && threadIdx.x < NB * 32) pCnt[threadIdx.x] = 0;
    int i = blockIdx.x * 256 + threadIdx.x;      // 196608
    int j  = i & 7;
    int l  = (i >> 3) & 63;
    int ks = (i >> 9) & 1;
    int rest = i >> 10;
    int f  = rest % 12;
    int kt = rest / 12;
    int mat = f >> 2, nt = f & 3;
    int n = nt * 16 + (l & 15);
    int k = kt * 64 + ks * 32 + (l >> 4) * 8 + j;
    const float* W = (mat == 0) ? Wk : ((mat == 1) ? Wq : Wv);
    wt[i] = f2bf(W[(size_t)k * 64 + n]);
}

// ---------------- kernel 1: fused QKV projection ----------------
__global__ __launch_bounds__(256) void proj(const float* __restrict__ x,
                                            const float* __restrict__ bk,
                                            const float* __restrict__ bq,
                                            const float* __restrict__ bv,
                                            const short* __restrict__ wt,
                                            short* __restrict__ ko,
                                            short* __restrict__ qo,
                                            short* __restrict__ vt) {
    __shared__ float xs[2][2048];
    __shared__ short ws2[2][12288];

    int tid = threadIdx.x;
    int wave = tid >> 6, lane = tid & 63;
    int quad = lane >> 4, l16 = lane & 15;
    int row0 = blockIdx.x * 32;
    int wbase = tid & ~63;

    floatx4 acc[2][3];
#pragma unroll
    for (int mt = 0; mt < 2; mt++)
#pragma unroll
        for (int fi = 0; fi < 3; fi++) acc[mt][fi] = (floatx4){0.f, 0.f, 0.f, 0.f};

    auto stage = [&](int kt, int buf) {
#pragma unroll
        for (int it = 0; it < 2; it++) {
            int s = it * 256 + tid;
            int r = s >> 4, p = s & 15;
            int c = (((p >> 1) ^ (r & 7)) << 1) | (p & 1);
            ld_lds16(x + (size_t)(row0 + r) * D_IN + kt * 64 + c * 4,
                     &xs[buf][(it * 256 + wbase) * 4]);
        }
#pragma unroll
        for (int it = 0; it < 6; it++) {
            int s = it * 256 + tid;
            ld_lds16(wt + (size_t)kt * 12288 + (size_t)s * 8,
                     &ws2[buf][(it * 256 + wbase) * 8]);
        }
    };

    stage(0, 0);
    for (int kt = 0; kt < 16; kt++) {
        int buf = kt & 1;
        __syncthreads();
        if (kt < 15) stage(kt + 1, buf ^ 1);
#pragma unroll
        for (int ks = 0; ks < 2; ks++) {
            short8 av[2];
#pragma unroll
            for (int mt = 0; mt < 2; mt++) {
                int r = mt * 16 + l16;
                int g = ks * 4 + quad;
                const float4* pp = reinterpret_cast<const float4*>(
                    &xs[buf][r * 64 + ((g ^ (r & 7)) << 1) * 4]);
                float4 f0 = pp[0], f1 = pp[1];
                union { uint32_t u[4]; short8 s; } cv;
                cv.u[0] = pk2(f0.x, f0.y); cv.u[1] = pk2(f0.z, f0.w);
                cv.u[2] = pk2(f1.x, f1.y); cv.u[3] = pk2(f1.z, f1.w);
                av[mt] = cv.s;
            }
#pragma unroll
            for (int fi = 0; fi < 3; fi++) {
                int f = wave * 3 + fi;
                short8 bf = *reinterpret_cast<const short8*>(
                    &ws2[buf][((f * 2 + ks) * 64 + lane) * 8]);
#pragma unroll
                for (int mt = 0; mt < 2; mt++)
                    acc[mt][fi] = __builtin_amdgcn_mfma_f32_16x16x32_bf16(av[mt], bf, acc[mt][fi], 0, 0, 0);
            }
        }
    }

#pragma unroll
    for (int fi = 0; fi < 3; fi++) {
        int f = wave * 3 + fi;
        int mat = f >> 2, nt = f & 3;
        int col = nt * 16 + l16;
        const float* bias = (mat == 0) ? bk : ((mat == 1) ? bq : bv);
        float bb = bias[col];
#pragma unroll
        for (int mt = 0; mt < 2; mt++)
#pragma unroll
            for (int reg = 0; reg < 4; reg++) {
                float v = acc[mt][fi][reg] + bb;
                int row = row0 + mt * 16 + quad * 4 + reg;
                if (mat == 0) ko[(size_t)row * HD + col] = f2bf(v * SL2E);
                else if (mat == 1) qo[(size_t)row * HD + col] = f2bf(v);
                else {
                    int bt = row >> 12, tl = row & 4095;
                    vt[(size_t)bt * HD * TLEN + (size_t)col * TLEN + tl] = f2bf(v);
                }
            }
    }
}

// ---------------- kernel 2: flash causal attention, M=128, split-K ----------------
// Computes S^T (A := staged q rows, B := per-wave k fragments). SPLIT=1 fuses the
// combine: last finishing block of each tile reduces the partials (L2-hot).
template<int SPLIT>
__global__ __launch_bounds__(256) void attn_kern(const short* __restrict__ kb,
                                                 const short* __restrict__ qb,
                                                 const short* __restrict__ vtw,
                                                 float* __restrict__ dst,   // SPLIT: pO ; else out
                                                 float* __restrict__ pL,
                                                 int* __restrict__ pCnt,
                                                 float* __restrict__ out) {
    __shared__ short Ks[2][4096];
    __shared__ short Vs[2][4096];
    __shared__ short Ps[128 * LDP];
    __shared__ int s_flag;

    int tid = threadIdx.x;
    int wave = tid >> 6, lane = tid & 63;
    int quad = lane >> 4, l16 = lane & 15;
    int wbase = tid & ~63;
    int batch = blockIdx.y;

    int tile, j0, j1, slot = 0, slot0 = 0, nparts = 0;
    if (SPLIT) {
        int bx = blockIdx.x;
        int t = 0, accb = 0;
        for (;;) { int p = (2 * t + 9) >> 3; if (bx < accb + p) break; accb += p; ++t; }
        tile = t;
        j0 = (bx - accb) * 8;
        int je = j0 + 8, lim = 2 * tile + 2;
        j1 = je < lim ? je : lim;
        slot = batch * PPB + bx;
        slot0 = batch * PPB + accb;
        nparts = (2 * tile + 9) >> 3;
    } else {
        tile = 31 - blockIdx.x;
        j0 = 0; j1 = 2 * tile + 2;
    }
    int t0 = tile * 128;
    int jd = 2 * tile;               // diagonal pair starts at j = jd
    size_t base = (size_t)batch * TLEN * HD;
    const short* vbase = vtw + (size_t)batch * HD * TLEN;

    short8 kf[2][2];                 // [mt][ks] pre-scaled k rows as B-fragments
#pragma unroll
    for (int mt = 0; mt < 2; mt++) {
        int trow = t0 + wave * 32 + mt * 16 + l16;
#pragma unroll
        for (int ks = 0; ks < 2; ks++)
            kf[mt][ks] = *reinterpret_cast<const short8*>(kb + base + (size_t)trow * HD + ks * 32 + quad * 8);
    }

    floatx4 o_acc[2][4];
#pragma unroll
    for (int mt = 0; mt < 2; mt++)
#pragma unroll
        for (int ht = 0; ht < 4; ht++) o_acc[mt][ht] = (floatx4){0.f, 0.f, 0.f, 0.f};
    float l_p[2] = {0.f, 0.f};

    auto stage = [&](int j, int buf) {
        int s0 = j * 64;
#pragma unroll
        for (int it = 0; it < 2; it++) {
            int s = it * 256 + tid;
            int r = s >> 3, c = (s & 7) ^ (r & 7);
            ld_lds16(qb + base + (size_t)(s0 + r) * HD + c * 8,
                     &Ks[buf][(it * 256 + wbase) * 8]);
            ld_lds16(vbase + (size_t)r * TLEN + s0 + c * 8,
                     &Vs[buf][(it * 256 + wbase) * 8]);
        }
    };

    stage(j0, 0);
    for (int j = j0; j < j1; ++j) {
        int buf = (j - j0) & 1;
        __syncthreads();
        if (j + 1 < j1) stage(j + 1, buf ^ 1);

        // waves 0-1 are fully causal-masked on the second diagonal sub-tile
        if (j == jd + 1 && wave < 2) continue;

        floatx4 sacc[2][4];
#pragma unroll
        for (int mt = 0; mt < 2; mt++)
#pragma unroll
            for (int nt = 0; nt < 4; nt++) sacc[mt][nt] = (floatx4){0.f, 0.f, 0.f, 0.f};
#pragma unroll
        for (int ks = 0; ks < 2; ks++)
#pragma unroll
            for (int nt = 0; nt < 4; nt++) {
                int r = nt * 16 + l16, g = ks * 4 + quad;
                short8 a = *reinterpret_cast<const short8*>(
                    &Ks[buf][r * 64 + (g ^ (r & 7)) * 8]);
#pragma unroll
                for (int mt = 0; mt < 2; mt++)
                    sacc[mt][nt] = __builtin_amdgcn_mfma_f32_16x16x32_bf16(a, kf[mt][ks], sacc[mt][nt], 0, 0, 0);
            }

        float pv[2][4][4];
#pragma unroll
        for (int mt = 0; mt < 2; mt++)
#pragma unroll
            for (int nt = 0; nt < 4; nt++)
#pragma unroll
                for (int reg = 0; reg < 4; reg++)
                    pv[mt][nt][reg] = __builtin_amdgcn_exp2f(sacc[mt][nt][reg]);
        if (j >= jd) {
            int s0 = j * 64;
#pragma unroll
            for (int mt = 0; mt < 2; mt++) {
                int t_g = t0 + wave * 32 + mt * 16 + l16;
#pragma unroll
                for (int nt = 0; nt < 4; nt++) {
                    int s_g = s0 + nt * 16 + quad * 4;
#pragma unroll
                    for (int reg = 0; reg < 4; reg++)
                        if (s_g + reg > t_g) pv[mt][nt][reg] = 0.f;
                }
            }
        }
#pragma unroll
        for (int mt = 0; mt < 2; mt++) {
            l_p[mt] += ((pv[mt][0][0] + pv[mt][0][1]) + (pv[mt][0][2] + pv[mt][0][3]))
                     + ((pv[mt][1][0] + pv[mt][1][1]) + (pv[mt][1][2] + pv[mt][1][3]))
                     + ((pv[mt][2][0] + pv[mt][2][1]) + (pv[mt][2][2] + pv[mt][2][3]))
                     + ((pv[mt][3][0] + pv[mt][3][1]) + (pv[mt][3][2] + pv[mt][3][3]));
#pragma unroll
            for (int nt = 0; nt < 4; nt++) {
                union { uint32_t u[2]; uint64_t q; } w;
                w.u[0] = pk2(pv[mt][nt][0], pv[mt][nt][1]);
                w.u[1] = pk2(pv[mt][nt][2], pv[mt][nt][3]);
                int row = wave * 32 + mt * 16 + l16;
                *reinterpret_cast<uint64_t*>(&Ps[row * LDP + nt * 16 + quad * 4]) = w.q;
            }
        }

#pragma unroll
        for (int ks = 0; ks < 2; ks++) {
            short8 a[2];
#pragma unroll
            for (int mt = 0; mt < 2; mt++)
                a[mt] = *reinterpret_cast<const short8*>(
                    &Ps[(wave * 32 + mt * 16 + l16) * LDP + ks * 32 + quad * 8]);
#pragma unroll
            for (int ht = 0; ht < 4; ht++) {
                int r = ht * 16 + l16, g = ks * 4 + quad;
                short8 b = *reinterpret_cast<const short8*>(
                    &Vs[buf][r * 64 + (g ^ (r & 7)) * 8]);
#pragma unroll
                for (int mt = 0; mt < 2; mt++)
                    o_acc[mt][ht] = __builtin_amdgcn_mfma_f32_16x16x32_bf16(a[mt], b, o_acc[mt][ht], 0, 0, 0);
            }
        }
    }

    // l reduction across quads: lane ends with L(t = l16 of its mt tile)
#pragma unroll
    for (int mt = 0; mt < 2; mt++) {
        l_p[mt] += __shfl_xor(l_p[mt], 16);
        l_p[mt] += __shfl_xor(l_p[mt], 32);
    }

    if (SPLIT) {
        float* po = dst + (size_t)slot * 8192;
#pragma unroll
        for (int mt = 0; mt < 2; mt++)
#pragma unroll
            for (int ht = 0; ht < 4; ht++)
#pragma unroll
                for (int reg = 0; reg < 4; reg++) {
                    int lr = wave * 32 + mt * 16 + quad * 4 + reg;
                    po[lr * 64 + ht * 16 + l16] = o_acc[mt][ht][reg];
                }
        if (quad == 0) {
#pragma unroll
            for (int mt = 0; mt < 2; mt++)
                pL[(size_t)slot * 128 + wave * 32 + mt * 16 + l16] = l_p[mt];
        }
        // --- last finishing block of this tile combines the partials ---
        __threadfence();
        __syncthreads();
        if (tid == 0) s_flag = atomicAdd(&pCnt[batch * 32 + tile], 1);
        __syncthreads();
        if (s_flag == nparts - 1) {
            __threadfence();
            int off = tid * 32;          // 32 contiguous floats per thread
            int row = off >> 6;
            float L = 0.f;
            float4 acc2[8];
#pragma unroll
            for (int i = 0; i < 8; i++) acc2[i] = (float4){0.f, 0.f, 0.f, 0.f};
            for (int p = 0; p < nparts; ++p) {
                int sl = slot0 + p;
                L += pL[(size_t)sl * 128 + row];
                const float4* src = reinterpret_cast<const float4*>(dst + (size_t)sl * 8192 + off);
#pragma unroll
                for (int i = 0; i < 8; i++) {
                    float4 v = src[i];
                    acc2[i].x += v.x; acc2[i].y += v.y; acc2[i].z += v.z; acc2[i].w += v.w;
                }
            }
            float inv = 1.0f / L;
            float4* dstp = reinterpret_cast<float4*>(out + base + (size_t)t0 * HD + off);
#pragma unroll
            for (int i = 0; i < 8; i++) {
                float4 v; v.x = acc2[i].x * inv; v.y = acc2[i].y * inv;
                v.z = acc2[i].z * inv; v.w = acc2[i].w * inv;
                dstp[i] = v;
            }
        }
    } else {
#pragma unroll
        for (int mt = 0; mt < 2; mt++) {
#pragma unroll
            for (int reg = 0; reg < 4; reg++) {
                float L = __shfl(l_p[mt], quad * 4 + reg, 64);
                float inv = 1.0f / L;
                int t = t0 + wave * 32 + mt * 16 + quad * 4 + reg;
#pragma unroll
                for (int ht = 0; ht < 4; ht++)
                    dst[base + (size_t)t * HD + ht * 16 + l16] = o_acc[mt][ht][reg] * inv;
            }
        }
    }
}

extern "C" void kernel_launch(void* const* d_in, const int* in_sizes, int n_in,
                              void* d_out, int out_size, void* d_ws, size_t ws_size,
                              hipStream_t stream) {
    const float* x  = (const float*)d_in[0];
    const float* Wk = (const float*)d_in[1];
    const float* bk = (const float*)d_in[2];
    const float* Wq = (const float*)d_in[3];
    const float* bq = (const float*)d_in[4];
    const float* Wv = (const float*)d_in[5];
    const float* bv = (const float*)d_in[6];
    float* out = (float*)d_out;

    const size_t nrow = (size_t)NB * TLEN;            // 16384
    short* ko = (short*)d_ws;                         // bf16 k (pre-scaled)      2 MB
    short* qo = ko + nrow * HD;                       // bf16 q                   2 MB
    short* vt = qo + nrow * HD;                       // bf16 v^T [4][64][4096]   2 MB
    short* wt = vt + nrow * HD;                       // bf16 wt frag-major       384 KB
    float* pO = (float*)(wt + 3 * 64 * 1024);         // partial O [4*144][128][64]
    float* pL = pO + (size_t)NB * PPB * 8192;         // partial l [4*144][128]
    int*  pCnt = (int*)(pL + (size_t)NB * PPB * 128); // split counters [4*32]
    size_t need = (size_t)((char*)(pCnt + NB * 32) - (char*)d_ws);

    prep_w<<<768, 256, 0, stream>>>(Wk, Wq, Wv, wt, pCnt);
    proj<<<512, 256, 0, stream>>>(x, bk, bq, bv, wt, ko, qo, vt);
    if (ws_size >= need) {
        attn_kern<1><<<dim3(PPB, NB), 256, 0, stream>>>(ko, qo, vt, pO, pL, pCnt, out);
    } else {
        attn_kern<0><<<dim3(32, NB), 256, 0, stream>>>(ko, qo, vt, out, nullptr, nullptr, out);
    }
}

// Round 7
// 156.245 us; speedup vs baseline: 1.6457x; 1.6457x over previous
//
#include <hip/hip_runtime.h>
#include <hip/hip_bf16.h>
#include <stdint.h>

typedef __attribute__((ext_vector_type(8))) short short8;
typedef __attribute__((ext_vector_type(4))) float floatx4;

#define HD 64
#define D_IN 1024
#define TLEN 4096
#define NB 4
#define PPB 144    // M=128 t-tiles: sum_{t=0}^{31} ceil((2t+2)/8)
#define LDP 72     // padded stride for P buffer (bf16 elems), 144 B (16B-aligned)
#define SL2E 0.18033688011112042f   // (1/sqrt(64)) * log2(e), folded into k

__device__ __forceinline__ short f2bf(float f) {
    union { float f; uint32_t u; } v{f};
    uint32_t u = v.u;
    uint32_t r = (u + 0x7FFFu + ((u >> 16) & 1u)) >> 16;
    return (short)r;
}

__device__ __forceinline__ uint32_t pk2(float a, float b) {
    __hip_bfloat162 h = __float22bfloat162_rn(float2{a, b});
    union { __hip_bfloat162 h; uint32_t u; } c{h};
    return c.u;
}

// async 16-B global->LDS copy (fire-and-forget, no VGPR round trip)
__device__ __forceinline__ void ld_lds16(const void* g, void* l) {
    __builtin_amdgcn_global_load_lds(
        (const __attribute__((address_space(1))) uint32_t*)g,
        (__attribute__((address_space(3))) uint32_t*)l, 16, 0, 0);
}

// ---------------- kernel 0: W -> fragment-major bf16 wt in ws ----------------
__global__ __launch_bounds__(256) void prep_w(const float* __restrict__ Wk,
                                              const float* __restrict__ Wq,
                                              const float* __restrict__ Wv,
                                              short* __restrict__ wt) {
    int i = blockIdx.x * 256 + threadIdx.x;      // 196608
    int j  = i & 7;
    int l  = (i >> 3) & 63;
    int ks = (i >> 9) & 1;
    int rest = i >> 10;
    int f  = rest % 12;
    int kt = rest / 12;
    int mat = f >> 2, nt = f & 3;
    int n = nt * 16 + (l & 15);
    int k = kt * 64 + ks * 32 + (l >> 4) * 8 + j;
    const float* W = (mat == 0) ? Wk : ((mat == 1) ? Wq : Wv);
    wt[i] = f2bf(W[(size_t)k * 64 + n]);
}

// ---------------- kernel 1: fused QKV projection ----------------
// 32 rows/block (512 blocks), double-buffered global_load_lds.
// k pre-scaled by SL2E. v stored transposed vt[b][h][t].
__global__ __launch_bounds__(256) void proj(const float* __restrict__ x,
                                            const float* __restrict__ bk,
                                            const float* __restrict__ bq,
                                            const float* __restrict__ bv,
                                            const short* __restrict__ wt,
                                            short* __restrict__ ko,
                                            short* __restrict__ qo,
                                            short* __restrict__ vt) {
    __shared__ float xs[2][2048];
    __shared__ short ws2[2][12288];

    int tid = threadIdx.x;
    int wave = tid >> 6, lane = tid & 63;
    int quad = lane >> 4, l16 = lane & 15;
    int row0 = blockIdx.x * 32;
    int wbase = tid & ~63;

    floatx4 acc[2][3];
#pragma unroll
    for (int mt = 0; mt < 2; mt++)
#pragma unroll
        for (int fi = 0; fi < 3; fi++) acc[mt][fi] = (floatx4){0.f, 0.f, 0.f, 0.f};

    auto stage = [&](int kt, int buf) {
#pragma unroll
        for (int it = 0; it < 2; it++) {
            int s = it * 256 + tid;
            int r = s >> 4, p = s & 15;
            int c = (((p >> 1) ^ (r & 7)) << 1) | (p & 1);
            ld_lds16(x + (size_t)(row0 + r) * D_IN + kt * 64 + c * 4,
                     &xs[buf][(it * 256 + wbase) * 4]);
        }
#pragma unroll
        for (int it = 0; it < 6; it++) {
            int s = it * 256 + tid;
            ld_lds16(wt + (size_t)kt * 12288 + (size_t)s * 8,
                     &ws2[buf][(it * 256 + wbase) * 8]);
        }
    };

    stage(0, 0);
    for (int kt = 0; kt < 16; kt++) {
        int buf = kt & 1;
        __syncthreads();
        if (kt < 15) stage(kt + 1, buf ^ 1);
#pragma unroll
        for (int ks = 0; ks < 2; ks++) {
            short8 av[2];
#pragma unroll
            for (int mt = 0; mt < 2; mt++) {
                int r = mt * 16 + l16;
                int g = ks * 4 + quad;
                const float4* pp = reinterpret_cast<const float4*>(
                    &xs[buf][r * 64 + ((g ^ (r & 7)) << 1) * 4]);
                float4 f0 = pp[0], f1 = pp[1];
                union { uint32_t u[4]; short8 s; } cv;
                cv.u[0] = pk2(f0.x, f0.y); cv.u[1] = pk2(f0.z, f0.w);
                cv.u[2] = pk2(f1.x, f1.y); cv.u[3] = pk2(f1.z, f1.w);
                av[mt] = cv.s;
            }
#pragma unroll
            for (int fi = 0; fi < 3; fi++) {
                int f = wave * 3 + fi;
                short8 bf = *reinterpret_cast<const short8*>(
                    &ws2[buf][((f * 2 + ks) * 64 + lane) * 8]);
#pragma unroll
                for (int mt = 0; mt < 2; mt++)
                    acc[mt][fi] = __builtin_amdgcn_mfma_f32_16x16x32_bf16(av[mt], bf, acc[mt][fi], 0, 0, 0);
            }
        }
    }

#pragma unroll
    for (int fi = 0; fi < 3; fi++) {
        int f = wave * 3 + fi;
        int mat = f >> 2, nt = f & 3;
        int col = nt * 16 + l16;
        const float* bias = (mat == 0) ? bk : ((mat == 1) ? bq : bv);
        float bb = bias[col];
#pragma unroll
        for (int mt = 0; mt < 2; mt++)
#pragma unroll
            for (int reg = 0; reg < 4; reg++) {
                float v = acc[mt][fi][reg] + bb;
                int row = row0 + mt * 16 + quad * 4 + reg;
                if (mat == 0) ko[(size_t)row * HD + col] = f2bf(v * SL2E);
                else if (mat == 1) qo[(size_t)row * HD + col] = f2bf(v);
                else {
                    int bt = row >> 12, tl = row & 4095;
                    vt[(size_t)bt * HD * TLEN + (size_t)col * TLEN + tl] = f2bf(v);
                }
            }
    }
}

// ---------------- kernel 2: flash causal attention, M=128, split-K ----------------
// Computes S^T (A := staged q rows from LDS, B := per-wave k fragments), so the
// P C-layout has t=l16 / s=quad*4+reg: packed b64 P-writes + cheap l handling.
// No device-scope fences: partials are combined by a separate kernel (G16 —
// fused combine w/ __threadfence cost ~110us in L2 writebacks, measured R6).
template<int SPLIT>
__global__ __launch_bounds__(256) void attn_kern(const short* __restrict__ kb,
                                                 const short* __restrict__ qb,
                                                 const short* __restrict__ vtw,
                                                 float* __restrict__ dst,   // SPLIT: pO ; else out
                                                 float* __restrict__ pL) {
    __shared__ short Ks[2][4096];   // 8 KB/buf: 64 s x 64 h, swizzled
    __shared__ short Vs[2][4096];   // 8 KB/buf: 64 h x 64 s, swizzled
    __shared__ short Ps[128 * LDP]; // P^T staging in [t][s] row-major

    int tid = threadIdx.x;
    int wave = tid >> 6, lane = tid & 63;
    int quad = lane >> 4, l16 = lane & 15;
    int wbase = tid & ~63;
    int batch = blockIdx.y;

    int tile, j0, j1, slot = 0;
    if (SPLIT) {
        int bx = blockIdx.x;
        int t = 0, accb = 0;
        for (;;) { int p = (2 * t + 9) >> 3; if (bx < accb + p) break; accb += p; ++t; }
        tile = t;
        j0 = (bx - accb) * 8;
        int je = j0 + 8, lim = 2 * tile + 2;
        j1 = je < lim ? je : lim;
        slot = batch * PPB + bx;
    } else {
        tile = 31 - blockIdx.x;
        j0 = 0; j1 = 2 * tile + 2;
    }
    int t0 = tile * 128;
    int jd = 2 * tile;               // diagonal pair starts at j = jd
    size_t base = (size_t)batch * TLEN * HD;
    const short* vbase = vtw + (size_t)batch * HD * TLEN;

    short8 kf[2][2];                 // [mt][ks] pre-scaled k rows as B-fragments
#pragma unroll
    for (int mt = 0; mt < 2; mt++) {
        int trow = t0 + wave * 32 + mt * 16 + l16;
#pragma unroll
        for (int ks = 0; ks < 2; ks++)
            kf[mt][ks] = *reinterpret_cast<const short8*>(kb + base + (size_t)trow * HD + ks * 32 + quad * 8);
    }

    floatx4 o_acc[2][4];
#pragma unroll
    for (int mt = 0; mt < 2; mt++)
#pragma unroll
        for (int ht = 0; ht < 4; ht++) o_acc[mt][ht] = (floatx4){0.f, 0.f, 0.f, 0.f};
    float l_p[2] = {0.f, 0.f};       // per-lane partial of l(t = l16 of mt tile)

    auto stage = [&](int j, int buf) {
        int s0 = j * 64;
#pragma unroll
        for (int it = 0; it < 2; it++) {
            int s = it * 256 + tid;
            int r = s >> 3, c = (s & 7) ^ (r & 7);
            ld_lds16(qb + base + (size_t)(s0 + r) * HD + c * 8,
                     &Ks[buf][(it * 256 + wbase) * 8]);
            ld_lds16(vbase + (size_t)r * TLEN + s0 + c * 8,
                     &Vs[buf][(it * 256 + wbase) * 8]);
        }
    };

    stage(j0, 0);
    for (int j = j0; j < j1; ++j) {
        int buf = (j - j0) & 1;
        __syncthreads();
        if (j + 1 < j1) stage(j + 1, buf ^ 1);

        // waves 0-1 are fully causal-masked on the second diagonal sub-tile
        if (j == jd + 1 && wave < 2) continue;

        // S^T = Qs(A) x kf(B): C[m=s][n=t], 16 MFMA, A-frags shared across mt
        floatx4 sacc[2][4];
#pragma unroll
        for (int mt = 0; mt < 2; mt++)
#pragma unroll
            for (int nt = 0; nt < 4; nt++) sacc[mt][nt] = (floatx4){0.f, 0.f, 0.f, 0.f};
#pragma unroll
        for (int ks = 0; ks < 2; ks++)
#pragma unroll
            for (int nt = 0; nt < 4; nt++) {
                int r = nt * 16 + l16, g = ks * 4 + quad;
                short8 a = *reinterpret_cast<const short8*>(
                    &Ks[buf][r * 64 + (g ^ (r & 7)) * 8]);
#pragma unroll
                for (int mt = 0; mt < 2; mt++)
                    sacc[mt][nt] = __builtin_amdgcn_mfma_f32_16x16x32_bf16(a, kf[mt][ks], sacc[mt][nt], 0, 0, 0);
            }

        // exp2 (k pre-scaled); causal mask only on the diagonal j-tiles
        float pv[2][4][4];
#pragma unroll
        for (int mt = 0; mt < 2; mt++)
#pragma unroll
            for (int nt = 0; nt < 4; nt++)
#pragma unroll
                for (int reg = 0; reg < 4; reg++)
                    pv[mt][nt][reg] = __builtin_amdgcn_exp2f(sacc[mt][nt][reg]);
        if (j >= jd) {
            int s0 = j * 64;
#pragma unroll
            for (int mt = 0; mt < 2; mt++) {
                int t_g = t0 + wave * 32 + mt * 16 + l16;
#pragma unroll
                for (int nt = 0; nt < 4; nt++) {
                    int s_g = s0 + nt * 16 + quad * 4;
#pragma unroll
                    for (int reg = 0; reg < 4; reg++)
                        if (s_g + reg > t_g) pv[mt][nt][reg] = 0.f;
                }
            }
        }
        // l partials (t = l16, pure per-lane adds) + packed P^T -> LDS (b64 writes)
#pragma unroll
        for (int mt = 0; mt < 2; mt++) {
            l_p[mt] += ((pv[mt][0][0] + pv[mt][0][1]) + (pv[mt][0][2] + pv[mt][0][3]))
                     + ((pv[mt][1][0] + pv[mt][1][1]) + (pv[mt][1][2] + pv[mt][1][3]))
                     + ((pv[mt][2][0] + pv[mt][2][1]) + (pv[mt][2][2] + pv[mt][2][3]))
                     + ((pv[mt][3][0] + pv[mt][3][1]) + (pv[mt][3][2] + pv[mt][3][3]));
#pragma unroll
            for (int nt = 0; nt < 4; nt++) {
                union { uint32_t u[2]; uint64_t q; } w;
                w.u[0] = pk2(pv[mt][nt][0], pv[mt][nt][1]);
                w.u[1] = pk2(pv[mt][nt][2], pv[mt][nt][3]);
                int row = wave * 32 + mt * 16 + l16;
                *reinterpret_cast<uint64_t*>(&Ps[row * LDP + nt * 16 + quad * 4]) = w.q;
            }
        }

        // O += P @ V : A = P (m=t=l16, k=s contiguous), B = V^T
#pragma unroll
        for (int ks = 0; ks < 2; ks++) {
            short8 a[2];
#pragma unroll
            for (int mt = 0; mt < 2; mt++)
                a[mt] = *reinterpret_cast<const short8*>(
                    &Ps[(wave * 32 + mt * 16 + l16) * LDP + ks * 32 + quad * 8]);
#pragma unroll
            for (int ht = 0; ht < 4; ht++) {
                int r = ht * 16 + l16, g = ks * 4 + quad;
                short8 b = *reinterpret_cast<const short8*>(
                    &Vs[buf][r * 64 + (g ^ (r & 7)) * 8]);
#pragma unroll
                for (int mt = 0; mt < 2; mt++)
                    o_acc[mt][ht] = __builtin_amdgcn_mfma_f32_16x16x32_bf16(a[mt], b, o_acc[mt][ht], 0, 0, 0);
            }
        }
    }

    // final l reduction across quads: every lane ends with L(t = l16 of its mt tile)
#pragma unroll
    for (int mt = 0; mt < 2; mt++) {
        l_p[mt] += __shfl_xor(l_p[mt], 16);
        l_p[mt] += __shfl_xor(l_p[mt], 32);
    }

    if (SPLIT) {
        float* po = dst + (size_t)slot * 8192;
#pragma unroll
        for (int mt = 0; mt < 2; mt++)
#pragma unroll
            for (int ht = 0; ht < 4; ht++)
#pragma unroll
                for (int reg = 0; reg < 4; reg++) {
                    int lr = wave * 32 + mt * 16 + quad * 4 + reg;
                    po[lr * 64 + ht * 16 + l16] = o_acc[mt][ht][reg];
                }
        if (quad == 0) {
#pragma unroll
            for (int mt = 0; mt < 2; mt++)
                pL[(size_t)slot * 128 + wave * 32 + mt * 16 + l16] = l_p[mt];
        }
    } else {
#pragma unroll
        for (int mt = 0; mt < 2; mt++) {
            // move L to the o_acc row layout: row t_loc = quad*4+reg needs L from lane l16=t_loc
#pragma unroll
            for (int reg = 0; reg < 4; reg++) {
                float L = __shfl(l_p[mt], quad * 4 + reg, 64);
                float inv = 1.0f / L;
                int t = t0 + wave * 32 + mt * 16 + quad * 4 + reg;
#pragma unroll
                for (int ht = 0; ht < 4; ht++)
                    dst[base + (size_t)t * HD + ht * 16 + l16] = o_acc[mt][ht][reg] * inv;
            }
        }
    }
}

// ---------------- kernel 3: combine split-K partials (coalesced) ----------------
__global__ __launch_bounds__(256) void attn_combine(const float* __restrict__ pO,
                                                    const float* __restrict__ pL,
                                                    float* __restrict__ out) {
    int tile = blockIdx.x, batch = blockIdx.y;
    int nparts = (2 * tile + 9) >> 3;
    int a = tile >> 2, r = tile & 3;
    int slot0 = batch * PPB + 2 * a * (a + 1) + r * (a + 1);
    int t = threadIdx.x;
    int off = t * 32;                 // thread owns 32 contiguous floats
    int row = off >> 6;

    float L = 0.f;
    float4 acc[8];
#pragma unroll
    for (int i = 0; i < 8; i++) acc[i] = (float4){0.f, 0.f, 0.f, 0.f};

    for (int p = 0; p < nparts; ++p) {
        int slot = slot0 + p;
        L += pL[(size_t)slot * 128 + row];
        const float4* src = reinterpret_cast<const float4*>(pO + (size_t)slot * 8192 + off);
#pragma unroll
        for (int i = 0; i < 8; i++) {
            float4 v = src[i];
            acc[i].x += v.x; acc[i].y += v.y; acc[i].z += v.z; acc[i].w += v.w;
        }
    }
    float inv = 1.0f / L;
    float4* dstp = reinterpret_cast<float4*>(out + (size_t)batch * TLEN * HD +
                                             (size_t)tile * 128 * HD + off);
#pragma unroll
    for (int i = 0; i < 8; i++) {
        float4 v; v.x = acc[i].x * inv; v.y = acc[i].y * inv; v.z = acc[i].z * inv; v.w = acc[i].w * inv;
        dstp[i] = v;
    }
}

extern "C" void kernel_launch(void* const* d_in, const int* in_sizes, int n_in,
                              void* d_out, int out_size, void* d_ws, size_t ws_size,
                              hipStream_t stream) {
    const float* x  = (const float*)d_in[0];
    const float* Wk = (const float*)d_in[1];
    const float* bk = (const float*)d_in[2];
    const float* Wq = (const float*)d_in[3];
    const float* bq = (const float*)d_in[4];
    const float* Wv = (const float*)d_in[5];
    const float* bv = (const float*)d_in[6];
    float* out = (float*)d_out;

    const size_t nrow = (size_t)NB * TLEN;            // 16384
    short* ko = (short*)d_ws;                         // bf16 k (pre-scaled)      2 MB
    short* qo = ko + nrow * HD;                       // bf16 q                   2 MB
    short* vt = qo + nrow * HD;                       // bf16 v^T [4][64][4096]   2 MB
    short* wt = vt + nrow * HD;                       // bf16 wt frag-major       384 KB
    float* pO = (float*)(wt + 3 * 64 * 1024);         // partial O [4*144][128][64]
    float* pL = pO + (size_t)NB * PPB * 8192;         // partial l [4*144][128]
    size_t need = (size_t)((char*)(pL + (size_t)NB * PPB * 128) - (char*)d_ws);

    prep_w<<<768, 256, 0, stream>>>(Wk, Wq, Wv, wt);
    proj<<<512, 256, 0, stream>>>(x, bk, bq, bv, wt, ko, qo, vt);
    if (ws_size >= need) {
        attn_kern<1><<<dim3(PPB, NB), 256, 0, stream>>>(ko, qo, vt, pO, pL);
        attn_combine<<<dim3(32, NB), 256, 0, stream>>>(pO, pL, out);
    } else {
        attn_kern<0><<<dim3(32, NB), 256, 0, stream>>>(ko, qo, vt, out, nullptr);
    }
}

// Round 8
// 154.102 us; speedup vs baseline: 1.6686x; 1.0139x over previous
//
#include <hip/hip_runtime.h>
#include <hip/hip_bf16.h>
#include <stdint.h>

typedef __attribute__((ext_vector_type(8))) short short8;
typedef __attribute__((ext_vector_type(4))) float floatx4;

#define HD 64
#define D_IN 1024
#define TLEN 4096
#define NB 4
#define PPB 144    // M=128 t-tiles: sum_{t=0}^{31} ceil((2t+2)/8)
#define LDP 72     // padded stride for P buffer (bf16 elems), 144 B (16B-aligned)
#define SL2E 0.18033688011112042f   // (1/sqrt(64)) * log2(e), folded into k

__device__ __forceinline__ short f2bf(float f) {
    union { float f; uint32_t u; } v{f};
    uint32_t u = v.u;
    uint32_t r = (u + 0x7FFFu + ((u >> 16) & 1u)) >> 16;
    return (short)r;
}

__device__ __forceinline__ float bf2f(short s) {
    union { uint32_t u; float f; } v;
    v.u = ((uint32_t)(uint16_t)s) << 16;
    return v.f;
}

__device__ __forceinline__ uint32_t pk2(float a, float b) {
    __hip_bfloat162 h = __float22bfloat162_rn(float2{a, b});
    union { __hip_bfloat162 h; uint32_t u; } c{h};
    return c.u;
}

// async 16-B global->LDS copy (fire-and-forget, no VGPR round trip)
__device__ __forceinline__ void ld_lds16(const void* g, void* l) {
    __builtin_amdgcn_global_load_lds(
        (const __attribute__((address_space(1))) uint32_t*)g,
        (__attribute__((address_space(3))) uint32_t*)l, 16, 0, 0);
}

// ---------------- kernel 0: W -> fragment-major bf16 wt in ws ----------------
__global__ __launch_bounds__(256) void prep_w(const float* __restrict__ Wk,
                                              const float* __restrict__ Wq,
                                              const float* __restrict__ Wv,
                                              short* __restrict__ wt) {
    int i = blockIdx.x * 256 + threadIdx.x;      // 196608
    int j  = i & 7;
    int l  = (i >> 3) & 63;
    int ks = (i >> 9) & 1;
    int rest = i >> 10;
    int f  = rest % 12;
    int kt = rest / 12;
    int mat = f >> 2, nt = f & 3;
    int n = nt * 16 + (l & 15);
    int k = kt * 64 + ks * 32 + (l >> 4) * 8 + j;
    const float* W = (mat == 0) ? Wk : ((mat == 1) ? Wq : Wv);
    wt[i] = f2bf(W[(size_t)k * 64 + n]);
}

// ---------------- kernel 1: fused QKV projection ----------------
// 32 rows/block (512 blocks), double-buffered global_load_lds.
// k pre-scaled by SL2E. v stored transposed vt[b][h][t].
__global__ __launch_bounds__(256) void proj(const float* __restrict__ x,
                                            const float* __restrict__ bk,
                                            const float* __restrict__ bq,
                                            const float* __restrict__ bv,
                                            const short* __restrict__ wt,
                                            short* __restrict__ ko,
                                            short* __restrict__ qo,
                                            short* __restrict__ vt) {
    __shared__ float xs[2][2048];
    __shared__ short ws2[2][12288];

    int tid = threadIdx.x;
    int wave = tid >> 6, lane = tid & 63;
    int quad = lane >> 4, l16 = lane & 15;
    int row0 = blockIdx.x * 32;
    int wbase = tid & ~63;

    floatx4 acc[2][3];
#pragma unroll
    for (int mt = 0; mt < 2; mt++)
#pragma unroll
        for (int fi = 0; fi < 3; fi++) acc[mt][fi] = (floatx4){0.f, 0.f, 0.f, 0.f};

    auto stage = [&](int kt, int buf) {
#pragma unroll
        for (int it = 0; it < 2; it++) {
            int s = it * 256 + tid;
            int r = s >> 4, p = s & 15;
            int c = (((p >> 1) ^ (r & 7)) << 1) | (p & 1);
            ld_lds16(x + (size_t)(row0 + r) * D_IN + kt * 64 + c * 4,
                     &xs[buf][(it * 256 + wbase) * 4]);
        }
#pragma unroll
        for (int it = 0; it < 6; it++) {
            int s = it * 256 + tid;
            ld_lds16(wt + (size_t)kt * 12288 + (size_t)s * 8,
                     &ws2[buf][(it * 256 + wbase) * 8]);
        }
    };

    stage(0, 0);
    for (int kt = 0; kt < 16; kt++) {
        int buf = kt & 1;
        __syncthreads();
        if (kt < 15) stage(kt + 1, buf ^ 1);
#pragma unroll
        for (int ks = 0; ks < 2; ks++) {
            short8 av[2];
#pragma unroll
            for (int mt = 0; mt < 2; mt++) {
                int r = mt * 16 + l16;
                int g = ks * 4 + quad;
                const float4* pp = reinterpret_cast<const float4*>(
                    &xs[buf][r * 64 + ((g ^ (r & 7)) << 1) * 4]);
                float4 f0 = pp[0], f1 = pp[1];
                union { uint32_t u[4]; short8 s; } cv;
                cv.u[0] = pk2(f0.x, f0.y); cv.u[1] = pk2(f0.z, f0.w);
                cv.u[2] = pk2(f1.x, f1.y); cv.u[3] = pk2(f1.z, f1.w);
                av[mt] = cv.s;
            }
#pragma unroll
            for (int fi = 0; fi < 3; fi++) {
                int f = wave * 3 + fi;
                short8 bf = *reinterpret_cast<const short8*>(
                    &ws2[buf][((f * 2 + ks) * 64 + lane) * 8]);
#pragma unroll
                for (int mt = 0; mt < 2; mt++)
                    acc[mt][fi] = __builtin_amdgcn_mfma_f32_16x16x32_bf16(av[mt], bf, acc[mt][fi], 0, 0, 0);
            }
        }
    }

#pragma unroll
    for (int fi = 0; fi < 3; fi++) {
        int f = wave * 3 + fi;
        int mat = f >> 2, nt = f & 3;
        int col = nt * 16 + l16;
        const float* bias = (mat == 0) ? bk : ((mat == 1) ? bq : bv);
        float bb = bias[col];
#pragma unroll
        for (int mt = 0; mt < 2; mt++)
#pragma unroll
            for (int reg = 0; reg < 4; reg++) {
                float v = acc[mt][fi][reg] + bb;
                int row = row0 + mt * 16 + quad * 4 + reg;
                if (mat == 0) ko[(size_t)row * HD + col] = f2bf(v * SL2E);
                else if (mat == 1) qo[(size_t)row * HD + col] = f2bf(v);
                else {
                    int bt = row >> 12, tl = row & 4095;
                    vt[(size_t)bt * HD * TLEN + (size_t)col * TLEN + tl] = f2bf(v);
                }
            }
    }
}

// ---------------- kernel 2: flash causal attention, M=128, split-K ----------------
// Computes S^T (A := staged q rows from LDS, B := per-wave k fragments).
// No device-scope fences (G16: fused combine w/ __threadfence cost ~110us, R6).
// Partials stored bf16 (plain sums of p*v, no cancellation). nparts==1 tiles
// normalize and write out directly, skipping the partial round-trip.
template<int SPLIT>
__global__ __launch_bounds__(256) void attn_kern(const short* __restrict__ kb,
                                                 const short* __restrict__ qb,
                                                 const short* __restrict__ vtw,
                                                 short* __restrict__ pO,
                                                 float* __restrict__ pL,
                                                 float* __restrict__ out) {
    __shared__ short Ks[2][4096];   // 8 KB/buf: 64 s x 64 h, swizzled
    __shared__ short Vs[2][4096];   // 8 KB/buf: 64 h x 64 s, swizzled
    __shared__ short Ps[128 * LDP]; // P^T staging in [t][s] row-major

    int tid = threadIdx.x;
    int wave = tid >> 6, lane = tid & 63;
    int quad = lane >> 4, l16 = lane & 15;
    int wbase = tid & ~63;
    int batch = blockIdx.y;

    int tile, j0, j1, slot = 0, nparts = 1;
    if (SPLIT) {
        int bx = blockIdx.x;
        int t = 0, accb = 0;
        for (;;) { int p = (2 * t + 9) >> 3; if (bx < accb + p) break; accb += p; ++t; }
        tile = t;
        j0 = (bx - accb) * 8;
        int je = j0 + 8, lim = 2 * tile + 2;
        j1 = je < lim ? je : lim;
        slot = batch * PPB + bx;
        nparts = (2 * tile + 9) >> 3;
    } else {
        tile = 31 - blockIdx.x;
        j0 = 0; j1 = 2 * tile + 2;
    }
    int t0 = tile * 128;
    int jd = 2 * tile;               // diagonal pair starts at j = jd
    size_t base = (size_t)batch * TLEN * HD;
    const short* vbase = vtw + (size_t)batch * HD * TLEN;

    short8 kf[2][2];                 // [mt][ks] pre-scaled k rows as B-fragments
#pragma unroll
    for (int mt = 0; mt < 2; mt++) {
        int trow = t0 + wave * 32 + mt * 16 + l16;
#pragma unroll
        for (int ks = 0; ks < 2; ks++)
            kf[mt][ks] = *reinterpret_cast<const short8*>(kb + base + (size_t)trow * HD + ks * 32 + quad * 8);
    }

    floatx4 o_acc[2][4];
#pragma unroll
    for (int mt = 0; mt < 2; mt++)
#pragma unroll
        for (int ht = 0; ht < 4; ht++) o_acc[mt][ht] = (floatx4){0.f, 0.f, 0.f, 0.f};
    float l_p[2] = {0.f, 0.f};       // per-lane partial of l(t = l16 of mt tile)

    auto stage = [&](int j, int buf) {
        int s0 = j * 64;
#pragma unroll
        for (int it = 0; it < 2; it++) {
            int s = it * 256 + tid;
            int r = s >> 3, c = (s & 7) ^ (r & 7);
            ld_lds16(qb + base + (size_t)(s0 + r) * HD + c * 8,
                     &Ks[buf][(it * 256 + wbase) * 8]);
            ld_lds16(vbase + (size_t)r * TLEN + s0 + c * 8,
                     &Vs[buf][(it * 256 + wbase) * 8]);
        }
    };

    stage(j0, 0);
    for (int j = j0; j < j1; ++j) {
        int buf = (j - j0) & 1;
        __syncthreads();
        if (j + 1 < j1) stage(j + 1, buf ^ 1);

        // waves 0-1 are fully causal-masked on the second diagonal sub-tile
        if (j == jd + 1 && wave < 2) continue;

        // S^T = Qs(A) x kf(B): C[m=s][n=t], 16 MFMA, A-frags shared across mt
        floatx4 sacc[2][4];
#pragma unroll
        for (int mt = 0; mt < 2; mt++)
#pragma unroll
            for (int nt = 0; nt < 4; nt++) sacc[mt][nt] = (floatx4){0.f, 0.f, 0.f, 0.f};
#pragma unroll
        for (int ks = 0; ks < 2; ks++)
#pragma unroll
            for (int nt = 0; nt < 4; nt++) {
                int r = nt * 16 + l16, g = ks * 4 + quad;
                short8 a = *reinterpret_cast<const short8*>(
                    &Ks[buf][r * 64 + (g ^ (r & 7)) * 8]);
#pragma unroll
                for (int mt = 0; mt < 2; mt++)
                    sacc[mt][nt] = __builtin_amdgcn_mfma_f32_16x16x32_bf16(a, kf[mt][ks], sacc[mt][nt], 0, 0, 0);
            }

        // exp2 (k pre-scaled); causal mask only on the diagonal j-tiles
        float pv[2][4][4];
#pragma unroll
        for (int mt = 0; mt < 2; mt++)
#pragma unroll
            for (int nt = 0; nt < 4; nt++)
#pragma unroll
                for (int reg = 0; reg < 4; reg++)
                    pv[mt][nt][reg] = __builtin_amdgcn_exp2f(sacc[mt][nt][reg]);
        if (j >= jd) {
            int s0 = j * 64;
#pragma unroll
            for (int mt = 0; mt < 2; mt++) {
                int t_g = t0 + wave * 32 + mt * 16 + l16;
#pragma unroll
                for (int nt = 0; nt < 4; nt++) {
                    int s_g = s0 + nt * 16 + quad * 4;
#pragma unroll
                    for (int reg = 0; reg < 4; reg++)
                        if (s_g + reg > t_g) pv[mt][nt][reg] = 0.f;
                }
            }
        }
        // l partials (t = l16, pure per-lane adds) + packed P^T -> LDS (b64 writes)
#pragma unroll
        for (int mt = 0; mt < 2; mt++) {
            l_p[mt] += ((pv[mt][0][0] + pv[mt][0][1]) + (pv[mt][0][2] + pv[mt][0][3]))
                     + ((pv[mt][1][0] + pv[mt][1][1]) + (pv[mt][1][2] + pv[mt][1][3]))
                     + ((pv[mt][2][0] + pv[mt][2][1]) + (pv[mt][2][2] + pv[mt][2][3]))
                     + ((pv[mt][3][0] + pv[mt][3][1]) + (pv[mt][3][2] + pv[mt][3][3]));
#pragma unroll
            for (int nt = 0; nt < 4; nt++) {
                union { uint32_t u[2]; uint64_t q; } w;
                w.u[0] = pk2(pv[mt][nt][0], pv[mt][nt][1]);
                w.u[1] = pk2(pv[mt][nt][2], pv[mt][nt][3]);
                int row = wave * 32 + mt * 16 + l16;
                *reinterpret_cast<uint64_t*>(&Ps[row * LDP + nt * 16 + quad * 4]) = w.q;
            }
        }

        // O += P @ V : A = P (m=t=l16, k=s contiguous), B = V^T
#pragma unroll
        for (int ks = 0; ks < 2; ks++) {
            short8 a[2];
#pragma unroll
            for (int mt = 0; mt < 2; mt++)
                a[mt] = *reinterpret_cast<const short8*>(
                    &Ps[(wave * 32 + mt * 16 + l16) * LDP + ks * 32 + quad * 8]);
#pragma unroll
            for (int ht = 0; ht < 4; ht++) {
                int r = ht * 16 + l16, g = ks * 4 + quad;
                short8 b = *reinterpret_cast<const short8*>(
                    &Vs[buf][r * 64 + (g ^ (r & 7)) * 8]);
#pragma unroll
                for (int mt = 0; mt < 2; mt++)
                    o_acc[mt][ht] = __builtin_amdgcn_mfma_f32_16x16x32_bf16(a[mt], b, o_acc[mt][ht], 0, 0, 0);
            }
        }
    }

    // final l reduction across quads: every lane ends with L(t = l16 of its mt tile)
#pragma unroll
    for (int mt = 0; mt < 2; mt++) {
        l_p[mt] += __shfl_xor(l_p[mt], 16);
        l_p[mt] += __shfl_xor(l_p[mt], 32);
    }

    if (SPLIT && nparts > 1) {
        short* po = pO + (size_t)slot * 8192;
#pragma unroll
        for (int mt = 0; mt < 2; mt++)
#pragma unroll
            for (int ht = 0; ht < 4; ht++)
#pragma unroll
                for (int reg = 0; reg < 4; reg++) {
                    int lr = wave * 32 + mt * 16 + quad * 4 + reg;
                    po[lr * 64 + ht * 16 + l16] = f2bf(o_acc[mt][ht][reg]);
                }
        if (quad == 0) {
#pragma unroll
            for (int mt = 0; mt < 2; mt++)
                pL[(size_t)slot * 128 + wave * 32 + mt * 16 + l16] = l_p[mt];
        }
    } else {
#pragma unroll
        for (int mt = 0; mt < 2; mt++) {
            // move L to the o_acc row layout: row t_loc = quad*4+reg needs L from lane l16=t_loc
#pragma unroll
            for (int reg = 0; reg < 4; reg++) {
                float L = __shfl(l_p[mt], quad * 4 + reg, 64);
                float inv = 1.0f / L;
                int t = t0 + wave * 32 + mt * 16 + quad * 4 + reg;
#pragma unroll
                for (int ht = 0; ht < 4; ht++)
                    out[base + (size_t)t * HD + ht * 16 + l16] = o_acc[mt][ht][reg] * inv;
            }
        }
    }
}

// ---------------- kernel 3: combine split-K partials (bf16, coalesced) ----------------
// Covers tiles 4..31 (nparts >= 2); tiles 0..3 were written directly by attn.
__global__ __launch_bounds__(256) void attn_combine(const short* __restrict__ pO,
                                                    const float* __restrict__ pL,
                                                    float* __restrict__ out) {
    int tile = blockIdx.x + 4, batch = blockIdx.y;
    int nparts = (2 * tile + 9) >> 3;
    int a = tile >> 2, r = tile & 3;
    int slot0 = batch * PPB + 2 * a * (a + 1) + r * (a + 1);
    int t = threadIdx.x;
    int off = t * 32;                 // 32 contiguous bf16 = half a row
    int row = off >> 6;
    int col0 = off & 63;

    float L = 0.f;
    float acc[32];
#pragma unroll
    for (int i = 0; i < 32; i++) acc[i] = 0.f;

    for (int p = 0; p < nparts; ++p) {
        int slot = slot0 + p;
        L += pL[(size_t)slot * 128 + row];
        const short* src = pO + (size_t)slot * 8192 + off;
#pragma unroll
        for (int c = 0; c < 4; c++) {
            short8 v = *reinterpret_cast<const short8*>(src + c * 8);
#pragma unroll
            for (int i = 0; i < 8; i++) acc[c * 8 + i] += bf2f(v[i]);
        }
    }
    float inv = 1.0f / L;
    float4* dstp = reinterpret_cast<float4*>(out + (size_t)batch * TLEN * HD +
                                             (size_t)(tile * 128 + row) * HD + col0);
#pragma unroll
    for (int c = 0; c < 8; c++) {
        float4 v;
        v.x = acc[c * 4 + 0] * inv; v.y = acc[c * 4 + 1] * inv;
        v.z = acc[c * 4 + 2] * inv; v.w = acc[c * 4 + 3] * inv;
        dstp[c] = v;
    }
}

extern "C" void kernel_launch(void* const* d_in, const int* in_sizes, int n_in,
                              void* d_out, int out_size, void* d_ws, size_t ws_size,
                              hipStream_t stream) {
    const float* x  = (const float*)d_in[0];
    const float* Wk = (const float*)d_in[1];
    const float* bk = (const float*)d_in[2];
    const float* Wq = (const float*)d_in[3];
    const float* bq = (const float*)d_in[4];
    const float* Wv = (const float*)d_in[5];
    const float* bv = (const float*)d_in[6];
    float* out = (float*)d_out;

    const size_t nrow = (size_t)NB * TLEN;            // 16384
    short* ko = (short*)d_ws;                         // bf16 k (pre-scaled)      2 MB
    short* qo = ko + nrow * HD;                       // bf16 q                   2 MB
    short* vt = qo + nrow * HD;                       // bf16 v^T [4][64][4096]   2 MB
    short* wt = vt + nrow * HD;                       // bf16 wt frag-major       384 KB
    short* pO = wt + 3 * 64 * 1024;                   // bf16 partial O [4*144][128][64]
    float* pL = (float*)(pO + (size_t)NB * PPB * 8192); // partial l [4*144][128]
    size_t need = (size_t)((char*)(pL + (size_t)NB * PPB * 128) - (char*)d_ws);

    prep_w<<<768, 256, 0, stream>>>(Wk, Wq, Wv, wt);
    proj<<<512, 256, 0, stream>>>(x, bk, bq, bv, wt, ko, qo, vt);
    if (ws_size >= need) {
        attn_kern<1><<<dim3(PPB, NB), 256, 0, stream>>>(ko, qo, vt, pO, pL, out);
        attn_combine<<<dim3(28, NB), 256, 0, stream>>>(pO, pL, out);
    } else {
        attn_kern<0><<<dim3(32, NB), 256, 0, stream>>>(ko, qo, vt, nullptr, nullptr, out);
    }
}